// Round 11
// baseline (33.565 us; speedup 1.0000x reference)
//
#include <hip/hip_runtime.h>
#include <hip/hip_bf16.h>
#include <math.h>

// ---------------------------------------------------------------------------
// HybridQuantumLinear via fixed-unitary GEMM (R10 + MFMA encode from R7).
//   k01: blocks 0..63  build U -> BtF (fragment order);
//        blocks 64..319 encode 32 rows each via MFMA (hi/lo bf16 split of x
//        and W_in, K=1024) -> tanh -> (cos,sin) -> outer-product-tree psi
//        -> psiF (fragment order) in HBM.  U-blocks co-dispatched with
//        encode blocks (R2 trick: no serial k1 tail).
//   k2:  256 blocks x 4 waves; 32 rows/block; wave -> 128 output cols.
//        psi_out = psi @ Bt^T via MFMA 16x16x32 (K=256, N=512);
//        P_i = re^2+im^2 ; z_q = sum sign_q(i) P_i ; out = z @ W_out^T.
// Fragment order F[tile16][kb][lane][8]: one wave's mfma fragment (tile,kb)
// is a contiguous 64-lane x 16B slab. A-frag: lane l = row tile*16 + l%16,
// k = kb*32 + (l/16)*8 + e. B-frag: col n = tile*16 + l%16, same k map.
// Amp index i: bit(7-q) = qubit q. In U-build, i = lane*4 + kk.
// ---------------------------------------------------------------------------

typedef __attribute__((ext_vector_type(8))) short bf16x8;
typedef __attribute__((ext_vector_type(4))) float f32x4;

static __device__ __forceinline__ unsigned short f2bf(float f) {
  __hip_bfloat16 h = __float2bfloat16(f);
  return *reinterpret_cast<unsigned short*>(&h);
}
static __device__ __forceinline__ float bf2f(unsigned short u) {
  unsigned int v = ((unsigned int)u) << 16;
  float r;
  __builtin_memcpy(&r, &v, 4);
  return r;
}

__device__ __forceinline__ float2 shfl_xor_f2(float2 v, int m) {
  float2 r;
  r.x = __shfl_xor(v.x, m, 64);
  r.y = __shfl_xor(v.y, m, 64);
  return r;
}
// acc += u*v (complex)
__device__ __forceinline__ float2 cfma(float2 u, float2 v, float2 acc) {
  acc.x = fmaf(u.x, v.x, fmaf(-u.y, v.y, acc.x));
  acc.y = fmaf(u.x, v.y, fmaf(u.y, v.x, acc.y));
  return acc;
}

// general 2x2 gate on qubit q
__device__ __forceinline__ void apply_gate(float2 (&a)[4], int q, float2 u00,
                                           float2 u01, float2 u10, float2 u11,
                                           int lane) {
  const float2 z0 = make_float2(0.f, 0.f);
  if (q == 7) {  // amp bit 0: pairs (0,1),(2,3)
    float2 n0 = cfma(u00, a[0], cfma(u01, a[1], z0));
    float2 n1 = cfma(u10, a[0], cfma(u11, a[1], z0));
    float2 n2 = cfma(u00, a[2], cfma(u01, a[3], z0));
    float2 n3 = cfma(u10, a[2], cfma(u11, a[3], z0));
    a[0] = n0; a[1] = n1; a[2] = n2; a[3] = n3;
  } else if (q == 6) {  // amp bit 1: pairs (0,2),(1,3)
    float2 n0 = cfma(u00, a[0], cfma(u01, a[2], z0));
    float2 n2 = cfma(u10, a[0], cfma(u11, a[2], z0));
    float2 n1 = cfma(u00, a[1], cfma(u01, a[3], z0));
    float2 n3 = cfma(u10, a[1], cfma(u11, a[3], z0));
    a[0] = n0; a[1] = n1; a[2] = n2; a[3] = n3;
  } else {  // lane bit (5-q)
    int m = 1 << (5 - q);
    bool b = (lane >> (5 - q)) & 1;
    float2 ca = b ? u11 : u00;
    float2 cp = b ? u10 : u01;
    #pragma unroll
    for (int k = 0; k < 4; ++k) {
      float2 p = shfl_xor_f2(a[k], m);
      a[k] = cfma(ca, a[k], cfma(cp, p, z0));
    }
  }
}

// CNOT(control q, target q+1)
__device__ __forceinline__ void apply_cnot(float2 (&a)[4], int q, int lane) {
  if (q <= 4) {
    int m = 1 << (4 - q);
    bool ctrl = (lane >> (5 - q)) & 1;
    #pragma unroll
    for (int k = 0; k < 4; ++k) {
      float2 p = shfl_xor_f2(a[k], m);
      a[k].x = ctrl ? p.x : a[k].x;
      a[k].y = ctrl ? p.y : a[k].y;
    }
  } else if (q == 5) {  // control = lane bit 0, target = k bit 1
    bool ct = lane & 1;
    float2 n0 = ct ? a[2] : a[0];
    float2 n1 = ct ? a[3] : a[1];
    float2 n2 = ct ? a[0] : a[2];
    float2 n3 = ct ? a[1] : a[3];
    a[0] = n0; a[1] = n1; a[2] = n2; a[3] = n3;
  } else {  // q == 6: control = k bit 1, target = k bit 0
    float2 t = a[2]; a[2] = a[3]; a[3] = t;
  }
}

__global__ __launch_bounds__(256) void k01_kernel(
    const float* __restrict__ x, const float* __restrict__ W_in,
    const float* __restrict__ theta, unsigned short* __restrict__ BtF,
    unsigned short* __restrict__ psiF, int B) {
  const int tid = threadIdx.x;
  const int lane = tid & 63;
  const int w = tid >> 6;
  const int cl = lane & 15;
  const int kg = lane >> 4;

  if (blockIdx.x < 64) {
    // ---------------- U-build (R10 verbatim) --------------------------------
    __shared__ float mats[32 * 8];
    if (tid < 32) {
      int l = tid >> 3, q = tid & 7;
      const float* th = theta + (l * 8 + q) * 3;
      float h1 = 0.5f * th[0], h2 = 0.5f * th[1], h3 = 0.5f * th[2];
      float c1 = cosf(h1), s1 = sinf(h1);
      float c2 = cosf(h2), s2 = sinf(h2);
      float c3 = cosf(h3), s3 = sinf(h3);
      float m00r = c2 * c1, m00i = s2 * s1;
      float m01r = -s2 * c1, m01i = -c2 * s1;
      float m10r = s2 * c1, m10i = -c2 * s1;
      float m11r = c1 * c2, m11i = -s1 * s2;
      float* o = &mats[tid * 8];
      o[0] = c3 * m00r + s3 * m00i;  o[1] = c3 * m00i - s3 * m00r;
      o[2] = c3 * m01r + s3 * m01i;  o[3] = c3 * m01i - s3 * m01r;
      o[4] = c3 * m10r - s3 * m10i;  o[5] = c3 * m10i + s3 * m10r;
      o[6] = c3 * m11r - s3 * m11i;  o[7] = c3 * m11i + s3 * m11r;
    }
    __syncthreads();

    const int j = blockIdx.x * 4 + w;  // basis column (= k index)
    float2 a[4];
    #pragma unroll
    for (int k = 0; k < 4; ++k)
      a[k] = make_float2((lane * 4 + k == j) ? 1.f : 0.f, 0.f);

    #pragma unroll
    for (int l = 0; l < 4; ++l) {
      #pragma unroll
      for (int q = 0; q < 8; ++q) {
        const float* m = &mats[(l * 8 + q) * 8];
        apply_gate(a, q, make_float2(m[0], m[1]), make_float2(m[2], m[3]),
                   make_float2(m[4], m[5]), make_float2(m[6], m[7]), lane);
      }
      #pragma unroll
      for (int i = (l & 1); i < 7; i += 2) apply_cnot(a, i, lane);
    }
    const int kb = j >> 5, kg7 = (j & 31) >> 3, e = j & 7;
    #pragma unroll
    for (int kk = 0; kk < 4; ++kk) {
      int i = lane * 4 + kk;
      #pragma unroll
      for (int c = 0; c < 2; ++c) {
        int n = 2 * i + c;
        float v = c ? a[kk].y : a[kk].x;
        size_t addr = (size_t)(((n >> 4) * 8 + kb) * 512) +
                      (kg7 * 16 + (n & 15)) * 8 + e;
        BtF[addr] = f2bf(v);
      }
    }
    return;
  }

  // ================== encode block: 32 rows via MFMA =======================
  __shared__ char Wlds[32768];      // W_in hi/lo bf16 [16][1024B], swizzled
  __shared__ float2 cs_lds[32][8];  // (cos,sin) per (row, qubit)
  const int rowbase = ((int)blockIdx.x - 64) * 32;

  // ---- stage W_in hi/lo (rows 8..15 zero) ----
  {
    const int q = tid >> 5;    // 0..7
    const int ch = tid & 31;   // 16 floats each
    const int swz = (q & 7) << 4;
    #pragma unroll
    for (int half = 0; half < 2; ++half) {
      float4 wa = *(const float4*)(W_in + q * 512 + ch * 16 + half * 8);
      float4 wb = *(const float4*)(W_in + q * 512 + ch * 16 + half * 8 + 4);
      float f[8] = {wa.x, wa.y, wa.z, wa.w, wb.x, wb.y, wb.z, wb.w};
      unsigned hv[4], lv[4];
      #pragma unroll
      for (int i = 0; i < 4; ++i) {
        unsigned short h0 = f2bf(f[2 * i]), h1 = f2bf(f[2 * i + 1]);
        unsigned short l0 = f2bf(f[2 * i] - bf2f(h0));
        unsigned short l1 = f2bf(f[2 * i + 1] - bf2f(h1));
        hv[i] = (unsigned)h0 | ((unsigned)h1 << 16);
        lv[i] = (unsigned)l0 | ((unsigned)l1 << 16);
      }
      *(uint4*)(Wlds + q * 2048 + ((ch * 32 + half * 16) ^ swz)) =
          make_uint4(hv[0], hv[1], hv[2], hv[3]);
      *(uint4*)(Wlds + q * 2048 + ((1024 + ch * 32 + half * 16) ^ swz)) =
          make_uint4(lv[0], lv[1], lv[2], lv[3]);
    }
    // zero rows 8..15 (B-frag cols 8..15, outputs discarded)
    const int zr = 8 + (tid >> 5);
    uint4 z4 = make_uint4(0, 0, 0, 0);
    #pragma unroll
    for (int i = 0; i < 4; ++i)
      *(uint4*)(Wlds + zr * 2048 + (tid & 31) * 64 + i * 16) = z4;
  }
  __syncthreads();

  // ---- G1: enc = x @ W_in^T (waves 0,1), hi/lo split, K=1024 ----
  if (w < 2) {
    const int rt = w;
    const float* xr = x + (size_t)(rowbase + rt * 16 + cl) * 512;
    f32x4 ea = (f32x4){0.f, 0.f, 0.f, 0.f};
    const int swz = (cl & 7) << 4;
    #pragma unroll
    for (int kb = 0; kb < 16; ++kb) {
      float4 xa = *(const float4*)(xr + kb * 32 + kg * 8);
      float4 xb = *(const float4*)(xr + kb * 32 + kg * 8 + 4);
      float f[8] = {xa.x, xa.y, xa.z, xa.w, xb.x, xb.y, xb.z, xb.w};
      bf16x8 hi8, lo8;
      #pragma unroll
      for (int i = 0; i < 8; ++i) {
        unsigned short h = f2bf(f[i]);
        hi8[i] = (short)h;
        lo8[i] = (short)f2bf(f[i] - bf2f(h));
      }
      bf16x8 bhi = *(const bf16x8*)(Wlds + cl * 2048 +
                                    ((kg * 16 + kb * 64) ^ swz));
      bf16x8 blo = *(const bf16x8*)(Wlds + cl * 2048 +
                                    ((1024 + kg * 16 + kb * 64) ^ swz));
      ea = __builtin_amdgcn_mfma_f32_16x16x32_bf16(hi8, bhi, ea, 0, 0, 0);
      ea = __builtin_amdgcn_mfma_f32_16x16x32_bf16(lo8, blo, ea, 0, 0, 0);
    }
    if (cl < 8) {
      #pragma unroll
      for (int jr = 0; jr < 4; ++jr) {
        float acc = ea[jr];
        float e  = __expf(2.f * acc);
        float th = 1.f - __fdividef(2.f, e + 1.f);  // tanh
        float h  = 1.57079632679489662f * th;       // (pi/2)*tanh
        cs_lds[rt * 16 + kg * 4 + jr][cl] = make_float2(__cosf(h), __sinf(h));
      }
    }
  }
  __syncthreads();

  // ---- psi assembly: thread -> (row r, 32 amps i = seg*32..seg*32+31) ----
  {
    const int r = tid >> 3;    // 0..31
    const int seg = tid & 7;   // amp bits 7..5 (qubits 0..2)
    const int b = rowbase + r;
    float2 g0 = cs_lds[r][0], g1 = cs_lds[r][1];
    float2 g2 = cs_lds[r][2], g3 = cs_lds[r][3];
    float2 g4 = cs_lds[r][4], g5 = cs_lds[r][5];
    float2 g6 = cs_lds[r][6], g7 = cs_lds[r][7];
    float pre = ((seg & 4) ? g0.y : g0.x) * ((seg & 2) ? g1.y : g1.x) *
                ((seg & 1) ? g2.y : g2.x);
    float p3[2], p4[4], p5[8], p6[16], p7[32];
    p3[0] = pre * g3.x; p3[1] = pre * g3.y;
    #pragma unroll
    for (int a = 0; a < 2; ++a) {
      p4[a * 2]     = p3[a] * g4.x;
      p4[a * 2 + 1] = p3[a] * g4.y;
    }
    #pragma unroll
    for (int a = 0; a < 4; ++a) {
      p5[a * 2]     = p4[a] * g5.x;
      p5[a * 2 + 1] = p4[a] * g5.y;
    }
    #pragma unroll
    for (int a = 0; a < 8; ++a) {
      p6[a * 2]     = p5[a] * g6.x;
      p6[a * 2 + 1] = p5[a] * g6.y;
    }
    #pragma unroll
    for (int a = 0; a < 16; ++a) {
      p7[a * 2]     = p6[a] * g7.x;
      p7[a * 2 + 1] = p6[a] * g7.y;
    }
    // psiF[b/16][kb=seg][g*16 + b%16][e], t = g*8 + e
    const size_t slab = (size_t)(((b >> 4) * 8 + seg) * 512);
    #pragma unroll
    for (int g = 0; g < 4; ++g) {
      unsigned u[4];
      #pragma unroll
      for (int i = 0; i < 4; ++i)
        u[i] = (unsigned)f2bf(p7[g * 8 + 2 * i]) |
               ((unsigned)f2bf(p7[g * 8 + 2 * i + 1]) << 16);
      *(uint4*)(psiF + slab + (g * 16 + (b & 15)) * 8) =
          make_uint4(u[0], u[1], u[2], u[3]);
    }
  }
}

__global__ __launch_bounds__(256, 1) void k2_kernel(
    const unsigned short* __restrict__ psiF,
    const unsigned short* __restrict__ BtF,
    const float* __restrict__ W_out, float* __restrict__ out) {
  __shared__ float z_lds[4][32][8];
  __shared__ float z_final[32][8];
  const int tid = threadIdx.x;
  const int lane = tid & 63;
  const int w = tid >> 6;
  const int rowbase = blockIdx.x * 32;
  const int cl = lane & 15;  // col-lane / A-row lane
  const int kg = lane >> 4;  // k-group

  const short* psis = (const short*)psiF;
  const short* Bts  = (const short*)BtF;

  // A fragments: contiguous slab per (rowtile, kb)
  bf16x8 Af[2][8];
  #pragma unroll
  for (int rt = 0; rt < 2; ++rt)
    #pragma unroll
    for (int kb = 0; kb < 8; ++kb)
      Af[rt][kb] = *(const bf16x8*)(psis +
          (size_t)((((rowbase >> 4) + rt) * 8 + kb) * 512) + lane * 8);

  const int wcol = w * 128;
  f32x4 acc[2][8];
  #pragma unroll
  for (int rt = 0; rt < 2; ++rt)
    #pragma unroll
    for (int ct = 0; ct < 8; ++ct) acc[rt][ct] = (f32x4){0.f, 0.f, 0.f, 0.f};

  #pragma unroll
  for (int ct = 0; ct < 8; ++ct) {
    const short* bp = Bts +
        (size_t)((((wcol >> 4) + ct) * 8) * 512) + lane * 8;
    bf16x8 Bf[8];
    #pragma unroll
    for (int kb = 0; kb < 8; ++kb) Bf[kb] = *(const bf16x8*)(bp + kb * 512);
    #pragma unroll
    for (int kb = 0; kb < 8; ++kb) {
      acc[0][ct] = __builtin_amdgcn_mfma_f32_16x16x32_bf16(Af[0][kb], Bf[kb],
                                                           acc[0][ct], 0, 0, 0);
      acc[1][ct] = __builtin_amdgcn_mfma_f32_16x16x32_bf16(Af[1][kb], Bf[kb],
                                                           acc[1][ct], 0, 0, 0);
    }
  }

  // ---- epilogue: P_i = re^2+im^2, z_q += sign * P. Even lanes do q0..3,
  // odd lanes q4..7 (partner lane holds the other component of the same i).
  float zacc[2][4][4];
  #pragma unroll
  for (int rt = 0; rt < 2; ++rt)
    #pragma unroll
    for (int u = 0; u < 4; ++u)
      #pragma unroll
      for (int jr = 0; jr < 4; ++jr) zacc[rt][u][jr] = 0.f;

  #pragma unroll
  for (int ct = 0; ct < 8; ++ct) {
    int n = wcol + ct * 16 + cl;
    int i = n >> 1;
    int ib = (lane & 1) ? (i & 15) : (i >> 4);
    float s[4];
    #pragma unroll
    for (int u = 0; u < 4; ++u)
      s[u] = ((ib >> (3 - u)) & 1) ? -1.f : 1.f;
    #pragma unroll
    for (int rt = 0; rt < 2; ++rt) {
      #pragma unroll
      for (int jr = 0; jr < 4; ++jr) {
        float v = acc[rt][ct][jr];
        v = v * v;
        float P = v + __shfl_xor(v, 1, 64);
        #pragma unroll
        for (int u = 0; u < 4; ++u)
          zacc[rt][u][jr] = fmaf(s[u], P, zacc[rt][u][jr]);
      }
    }
  }

  // reduce over same-parity col-lanes (lane bits 1..3)
  #pragma unroll
  for (int m = 2; m <= 8; m <<= 1)
    #pragma unroll
    for (int rt = 0; rt < 2; ++rt)
      #pragma unroll
      for (int u = 0; u < 4; ++u)
        #pragma unroll
        for (int jr = 0; jr < 4; ++jr)
          zacc[rt][u][jr] += __shfl_xor(zacc[rt][u][jr], m, 64);

  if (cl <= 1) {
    #pragma unroll
    for (int rt = 0; rt < 2; ++rt)
      #pragma unroll
      for (int u = 0; u < 4; ++u)
        #pragma unroll
        for (int jr = 0; jr < 4; ++jr)
          z_lds[w][rt * 16 + kg * 4 + jr][(lane & 1) * 4 + u] = zacc[rt][u][jr];
  }
  __syncthreads();

  {  // sum the 4 wave-partials
    int r = tid >> 3, q = tid & 7;
    z_final[r][q] = z_lds[0][r][q] + z_lds[1][r][q] + z_lds[2][r][q] +
                    z_lds[3][r][q];
  }
  __syncthreads();

  // ---- out = z @ W_out^T ----
  const int o0 = tid, o1 = 256 + tid;
  float4 wa0 = *(const float4*)(W_out + o0 * 8);
  float4 wb0 = *(const float4*)(W_out + o0 * 8 + 4);
  float4 wa1 = *(const float4*)(W_out + o1 * 8);
  float4 wb1 = *(const float4*)(W_out + o1 * 8 + 4);
  #pragma unroll 4
  for (int r = 0; r < 32; ++r) {
    float4 z0 = *(const float4*)&z_final[r][0];
    float4 z1 = *(const float4*)&z_final[r][4];
    float d0 = wa0.x * z0.x + wa0.y * z0.y + wa0.z * z0.z + wa0.w * z0.w +
               wb0.x * z1.x + wb0.y * z1.y + wb0.z * z1.z + wb0.w * z1.w;
    float d1 = wa1.x * z0.x + wa1.y * z0.y + wa1.z * z0.z + wa1.w * z0.w +
               wb1.x * z1.x + wb1.y * z1.y + wb1.z * z1.z + wb1.w * z1.w;
    out[(size_t)(rowbase + r) * 512 + o0] = d0;
    out[(size_t)(rowbase + r) * 512 + o1] = d1;
  }
}

extern "C" void kernel_launch(void* const* d_in, const int* in_sizes, int n_in,
                              void* d_out, int out_size, void* d_ws, size_t ws_size,
                              hipStream_t stream) {
  const float* x     = (const float*)d_in[0];  // (B, 512)
  const float* W_in  = (const float*)d_in[1];  // (8, 512)
  const float* W_out = (const float*)d_in[2];  // (512, 8)
  const float* theta = (const float*)d_in[3];  // (4, 8, 3)
  float* out = (float*)d_out;

  const int B = in_sizes[0] / 512;  // 8192
  // BtF: 32 coltiles x 8 kb x 512 shorts = 256 KiB
  const size_t btBytes = (size_t)32 * 8 * 512 * sizeof(short);

  unsigned short* BtF  = (unsigned short*)d_ws;
  unsigned short* psiF = (unsigned short*)((char*)d_ws + btBytes);

  hipLaunchKernelGGL(k01_kernel, dim3(64 + B / 32), dim3(256), 0, stream,
                     x, W_in, theta, BtF, psiF, B);
  hipLaunchKernelGGL(k2_kernel, dim3(B / 32), dim3(256), 0, stream,
                     psiF, BtF, W_out, out);
}

// Round 12
// 33.010 us; speedup vs baseline: 1.0168x; 1.0168x over previous
//
#include <hip/hip_runtime.h>
#include <hip/hip_bf16.h>
#include <math.h>

// ---------------------------------------------------------------------------
// HybridQuantumLinear via fixed-unitary GEMM (R10 + k2 at 2 blocks/CU).
//   k01: blocks 0..63 build U -> BtF (fragment order);
//        blocks 64.. encode: enc=tanh(x@W_in^T)*pi -> psiF (fragment order).
//   k2:  512 blocks x 4 waves; block = 16 batch rows; wave = 128 output cols;
//        2 blocks/CU co-resident (phase overlap across blocks).
//        psi_out = psi @ Bt^T via MFMA 16x16x32 (K=256, N=512);
//        P_i = re^2+im^2 ; z_q = sum sign_q(i) P_i ; out = z @ W_out^T.
// Fragment order F[tile16][kb][lane][8]: one wave's mfma fragment (tile,kb)
// is a contiguous 64-lane x 16B slab. A-frag: lane l = row tile*16 + l%16,
// k = kb*32 + (l/16)*8 + e. B-frag: col n = tile*16 + l%16, same k map.
// Amp index i: bit(7-q) = qubit q. In U-build, i = lane*4 + kk.
// ---------------------------------------------------------------------------

typedef __attribute__((ext_vector_type(8))) short bf16x8;
typedef __attribute__((ext_vector_type(4))) float f32x4;

static __device__ __forceinline__ unsigned short f2bf(float f) {
  __hip_bfloat16 h = __float2bfloat16(f);
  return *reinterpret_cast<unsigned short*>(&h);
}

__device__ __forceinline__ float2 shfl_xor_f2(float2 v, int m) {
  float2 r;
  r.x = __shfl_xor(v.x, m, 64);
  r.y = __shfl_xor(v.y, m, 64);
  return r;
}
// acc += u*v (complex)
__device__ __forceinline__ float2 cfma(float2 u, float2 v, float2 acc) {
  acc.x = fmaf(u.x, v.x, fmaf(-u.y, v.y, acc.x));
  acc.y = fmaf(u.x, v.y, fmaf(u.y, v.x, acc.y));
  return acc;
}

// general 2x2 gate on qubit q
__device__ __forceinline__ void apply_gate(float2 (&a)[4], int q, float2 u00,
                                           float2 u01, float2 u10, float2 u11,
                                           int lane) {
  const float2 z0 = make_float2(0.f, 0.f);
  if (q == 7) {  // amp bit 0: pairs (0,1),(2,3)
    float2 n0 = cfma(u00, a[0], cfma(u01, a[1], z0));
    float2 n1 = cfma(u10, a[0], cfma(u11, a[1], z0));
    float2 n2 = cfma(u00, a[2], cfma(u01, a[3], z0));
    float2 n3 = cfma(u10, a[2], cfma(u11, a[3], z0));
    a[0] = n0; a[1] = n1; a[2] = n2; a[3] = n3;
  } else if (q == 6) {  // amp bit 1: pairs (0,2),(1,3)
    float2 n0 = cfma(u00, a[0], cfma(u01, a[2], z0));
    float2 n2 = cfma(u10, a[0], cfma(u11, a[2], z0));
    float2 n1 = cfma(u00, a[1], cfma(u01, a[3], z0));
    float2 n3 = cfma(u10, a[1], cfma(u11, a[3], z0));
    a[0] = n0; a[1] = n1; a[2] = n2; a[3] = n3;
  } else {  // lane bit (5-q)
    int m = 1 << (5 - q);
    bool b = (lane >> (5 - q)) & 1;
    float2 ca = b ? u11 : u00;
    float2 cp = b ? u10 : u01;
    #pragma unroll
    for (int k = 0; k < 4; ++k) {
      float2 p = shfl_xor_f2(a[k], m);
      a[k] = cfma(ca, a[k], cfma(cp, p, z0));
    }
  }
}

// CNOT(control q, target q+1)
__device__ __forceinline__ void apply_cnot(float2 (&a)[4], int q, int lane) {
  if (q <= 4) {
    int m = 1 << (4 - q);
    bool ctrl = (lane >> (5 - q)) & 1;
    #pragma unroll
    for (int k = 0; k < 4; ++k) {
      float2 p = shfl_xor_f2(a[k], m);
      a[k].x = ctrl ? p.x : a[k].x;
      a[k].y = ctrl ? p.y : a[k].y;
    }
  } else if (q == 5) {  // control = lane bit 0, target = k bit 1
    bool ct = lane & 1;
    float2 n0 = ct ? a[2] : a[0];
    float2 n1 = ct ? a[3] : a[1];
    float2 n2 = ct ? a[0] : a[2];
    float2 n3 = ct ? a[1] : a[3];
    a[0] = n0; a[1] = n1; a[2] = n2; a[3] = n3;
  } else {  // q == 6: control = k bit 1, target = k bit 0
    float2 t = a[2]; a[2] = a[3]; a[3] = t;
  }
}

__global__ __launch_bounds__(256) void k01_kernel(
    const float* __restrict__ x, const float* __restrict__ W_in,
    const float* __restrict__ theta, unsigned short* __restrict__ BtF,
    unsigned short* __restrict__ psiF, int B) {
  __shared__ float mats[32 * 8];
  const int tid = threadIdx.x;
  const int lane = tid & 63;

  if (blockIdx.x < 64) {
    // ---------------- U-build: fused gate matrices, then basis-state sim ----
    if (tid < 32) {
      int l = tid >> 3, q = tid & 7;
      const float* th = theta + (l * 8 + q) * 3;
      float h1 = 0.5f * th[0], h2 = 0.5f * th[1], h3 = 0.5f * th[2];
      float c1 = cosf(h1), s1 = sinf(h1);
      float c2 = cosf(h2), s2 = sinf(h2);
      float c3 = cosf(h3), s3 = sinf(h3);
      // M = RY*RX
      float m00r = c2 * c1, m00i = s2 * s1;
      float m01r = -s2 * c1, m01i = -c2 * s1;
      float m10r = s2 * c1, m10i = -c2 * s1;
      float m11r = c1 * c2, m11i = -s1 * s2;
      // U = RZ*M: row0 *= (c3 - i s3), row1 *= (c3 + i s3)
      float* o = &mats[tid * 8];
      o[0] = c3 * m00r + s3 * m00i;  o[1] = c3 * m00i - s3 * m00r;
      o[2] = c3 * m01r + s3 * m01i;  o[3] = c3 * m01i - s3 * m01r;
      o[4] = c3 * m10r - s3 * m10i;  o[5] = c3 * m10i + s3 * m10r;
      o[6] = c3 * m11r - s3 * m11i;  o[7] = c3 * m11i + s3 * m11r;
    }
    __syncthreads();

    const int j = blockIdx.x * 4 + (tid >> 6);  // basis column (= k index)
    float2 a[4];
    #pragma unroll
    for (int k = 0; k < 4; ++k)
      a[k] = make_float2((lane * 4 + k == j) ? 1.f : 0.f, 0.f);

    #pragma unroll
    for (int l = 0; l < 4; ++l) {
      #pragma unroll
      for (int q = 0; q < 8; ++q) {
        const float* m = &mats[(l * 8 + q) * 8];
        float2 u00 = make_float2(m[0], m[1]);
        float2 u01 = make_float2(m[2], m[3]);
        float2 u10 = make_float2(m[4], m[5]);
        float2 u11 = make_float2(m[6], m[7]);
        apply_gate(a, q, u00, u01, u10, u11, lane);
      }
      #pragma unroll
      for (int i = (l & 1); i < 7; i += 2) apply_cnot(a, i, lane);
    }
    // BtF[n/16][j/32][((j%32)/8)*16 + n%16][j%8], n = 2i+c, i = lane*4+kk
    const int kb = j >> 5, kg7 = (j & 31) >> 3, e = j & 7;
    #pragma unroll
    for (int kk = 0; kk < 4; ++kk) {
      int i = lane * 4 + kk;
      #pragma unroll
      for (int c = 0; c < 2; ++c) {
        int n = 2 * i + c;
        float v = c ? a[kk].y : a[kk].x;
        size_t addr = (size_t)(((n >> 4) * 8 + kb) * 512) +
                      (kg7 * 16 + (n & 15)) * 8 + e;
        BtF[addr] = f2bf(v);
      }
    }
    return;
  }

  // ---------------- encoding + psi_in ----------------
  const int b = (int)(blockIdx.x - 64) * 4 + (tid >> 6);
  if (b >= B) return;

  float xv[8];
  #pragma unroll
  for (int j = 0; j < 8; ++j) xv[j] = x[b * 512 + j * 64 + lane];

  float acc[8];
  #pragma unroll
  for (int q = 0; q < 8; ++q) {
    float s = 0.f;
    #pragma unroll
    for (int j = 0; j < 8; ++j)
      s = fmaf(xv[j], W_in[q * 512 + j * 64 + lane], s);
    acc[q] = s;
  }
  #pragma unroll
  for (int m = 1; m < 64; m <<= 1) {
    #pragma unroll
    for (int q = 0; q < 8; ++q) acc[q] += __shfl_xor(acc[q], m, 64);
  }

  float cq[8], sq[8];
  #pragma unroll
  for (int q = 0; q < 8; ++q) {
    float e  = __expf(2.f * acc[q]);
    float th = 1.f - __fdividef(2.f, e + 1.f);  // tanh
    float h  = 1.57079632679489662f * th;       // (pi/2) * tanh
    cq[q] = __cosf(h);
    sq[q] = __sinf(h);
  }

  float base = 1.f;
  #pragma unroll
  for (int q = 0; q < 6; ++q)
    base *= ((lane >> (5 - q)) & 1) ? sq[q] : cq[q];

  __hip_bfloat16 h4[4];
  h4[0] = __float2bfloat16(base * cq[6] * cq[7]);
  h4[1] = __float2bfloat16(base * cq[6] * sq[7]);
  h4[2] = __float2bfloat16(base * sq[6] * cq[7]);
  h4[3] = __float2bfloat16(base * sq[6] * sq[7]);
  uint2 pk = *reinterpret_cast<uint2*>(h4);
  // lane holds k = lane*4 .. lane*4+3 of row b:
  // psiF[b/16][lane/8][((lane%8)/2)*16 + b%16][(lane%2)*4], 8B store
  size_t addr = (size_t)(((b >> 4) * 8 + (lane >> 3)) * 512) +
                (((lane & 7) >> 1) * 16 + (b & 15)) * 8 + (lane & 1) * 4;
  *reinterpret_cast<uint2*>(psiF + addr) = pk;
}

__global__ __launch_bounds__(256, 2) void k2_kernel(
    const unsigned short* __restrict__ psiF,
    const unsigned short* __restrict__ BtF,
    const float* __restrict__ W_out, float* __restrict__ out) {
  __shared__ float z_lds[4][16][8];
  __shared__ float z_final[16][8];
  const int tid = threadIdx.x;
  const int lane = tid & 63;
  const int w = tid >> 6;
  const int rowbase = blockIdx.x * 16;
  const int cl = lane & 15;  // col-lane / A-row lane
  const int kg = lane >> 4;  // k-group

  const short* psis = (const short*)psiF;
  const short* Bts  = (const short*)BtF;

  // A fragments: contiguous slab per kb (single 16-row tile)
  bf16x8 Af[8];
  #pragma unroll
  for (int kb = 0; kb < 8; ++kb)
    Af[kb] = *(const bf16x8*)(psis +
        (size_t)(((rowbase >> 4) * 8 + kb) * 512) + lane * 8);

  const int wcol = w * 128;
  f32x4 acc[8];
  #pragma unroll
  for (int ct = 0; ct < 8; ++ct) acc[ct] = (f32x4){0.f, 0.f, 0.f, 0.f};

  #pragma unroll
  for (int ct = 0; ct < 8; ++ct) {
    const short* bp = Bts +
        (size_t)((((wcol >> 4) + ct) * 8) * 512) + lane * 8;
    bf16x8 Bf[8];
    #pragma unroll
    for (int kb = 0; kb < 8; ++kb) Bf[kb] = *(const bf16x8*)(bp + kb * 512);
    #pragma unroll
    for (int kb = 0; kb < 8; ++kb)
      acc[ct] = __builtin_amdgcn_mfma_f32_16x16x32_bf16(Af[kb], Bf[kb],
                                                        acc[ct], 0, 0, 0);
  }

  // ---- epilogue: P_i = re^2+im^2, z_q += sign * P. Even lanes do q0..3,
  // odd lanes q4..7 (partner lane holds the other component of the same i).
  float zacc[4][4];
  #pragma unroll
  for (int u = 0; u < 4; ++u)
    #pragma unroll
    for (int jr = 0; jr < 4; ++jr) zacc[u][jr] = 0.f;

  #pragma unroll
  for (int ct = 0; ct < 8; ++ct) {
    int n = wcol + ct * 16 + cl;
    int i = n >> 1;
    int ib = (lane & 1) ? (i & 15) : (i >> 4);
    float s[4];
    #pragma unroll
    for (int u = 0; u < 4; ++u)
      s[u] = ((ib >> (3 - u)) & 1) ? -1.f : 1.f;
    #pragma unroll
    for (int jr = 0; jr < 4; ++jr) {
      float v = acc[ct][jr];
      v = v * v;
      float P = v + __shfl_xor(v, 1, 64);
      #pragma unroll
      for (int u = 0; u < 4; ++u)
        zacc[u][jr] = fmaf(s[u], P, zacc[u][jr]);
    }
  }

  // reduce over same-parity col-lanes (lane bits 1..3)
  #pragma unroll
  for (int m = 2; m <= 8; m <<= 1)
    #pragma unroll
    for (int u = 0; u < 4; ++u)
      #pragma unroll
      for (int jr = 0; jr < 4; ++jr)
        zacc[u][jr] += __shfl_xor(zacc[u][jr], m, 64);

  if (cl <= 1) {
    #pragma unroll
    for (int u = 0; u < 4; ++u)
      #pragma unroll
      for (int jr = 0; jr < 4; ++jr)
        z_lds[w][kg * 4 + jr][(lane & 1) * 4 + u] = zacc[u][jr];
  }
  __syncthreads();

  if (tid < 128) {  // sum the 4 wave-partials
    int r = tid >> 3, q = tid & 7;
    z_final[r][q] = z_lds[0][r][q] + z_lds[1][r][q] + z_lds[2][r][q] +
                    z_lds[3][r][q];
  }
  __syncthreads();

  // ---- out = z @ W_out^T : thread -> cols 2*tid, 2*tid+1 ------------------
  const int o0 = tid * 2;
  float4 wa0 = *(const float4*)(W_out + (size_t)o0 * 8);
  float4 wb0 = *(const float4*)(W_out + (size_t)o0 * 8 + 4);
  float4 wa1 = *(const float4*)(W_out + (size_t)o0 * 8 + 8);
  float4 wb1 = *(const float4*)(W_out + (size_t)o0 * 8 + 12);
  #pragma unroll 4
  for (int r = 0; r < 16; ++r) {
    float4 z0 = *(const float4*)&z_final[r][0];
    float4 z1 = *(const float4*)&z_final[r][4];
    float2 d;
    d.x = wa0.x * z0.x + wa0.y * z0.y + wa0.z * z0.z + wa0.w * z0.w +
          wb0.x * z1.x + wb0.y * z1.y + wb0.z * z1.z + wb0.w * z1.w;
    d.y = wa1.x * z0.x + wa1.y * z0.y + wa1.z * z0.z + wa1.w * z0.w +
          wb1.x * z1.x + wb1.y * z1.y + wb1.z * z1.z + wb1.w * z1.w;
    *(float2*)(out + (size_t)(rowbase + r) * 512 + o0) = d;
  }
}

extern "C" void kernel_launch(void* const* d_in, const int* in_sizes, int n_in,
                              void* d_out, int out_size, void* d_ws, size_t ws_size,
                              hipStream_t stream) {
  const float* x     = (const float*)d_in[0];  // (B, 512)
  const float* W_in  = (const float*)d_in[1];  // (8, 512)
  const float* W_out = (const float*)d_in[2];  // (512, 8)
  const float* theta = (const float*)d_in[3];  // (4, 8, 3)
  float* out = (float*)d_out;

  const int B = in_sizes[0] / 512;  // 8192
  // BtF: 32 coltiles x 8 kb x 512 shorts = 256 KiB
  const size_t btBytes = (size_t)32 * 8 * 512 * sizeof(short);

  unsigned short* BtF  = (unsigned short*)d_ws;
  unsigned short* psiF = (unsigned short*)((char*)d_ws + btBytes);

  hipLaunchKernelGGL(k01_kernel, dim3(64 + B / 4), dim3(256), 0, stream,
                     x, W_in, theta, BtF, psiF, B);
  hipLaunchKernelGGL(k2_kernel, dim3(B / 16), dim3(256), 0, stream,
                     psiF, BtF, W_out, out);
}